// Round 1
// baseline (58080.585 us; speedup 1.0000x reference)
//
#include <hip/hip_runtime.h>
#include <math.h>

#define DM   1024
#define BSZ  4
#define LSEQ 4096
#define NW   64            // workgroups in scan (all-resident: 64 <= 256 CUs)
#define RPW  16            // DM / NW rows per WG
#define TPB  256
#define HROW 1088          // padded floats per batch row in LDS (16 segs * 68)
#define PRW  68            // padded seg stride (64 data + 4 pad) -> no bank conflicts

// ---------------- Phase 1: bx = x @ B_w^T (fp32 NT GEMM) ----------------
// out[m][n] = sum_k X[m][k] * Bw[n][k];  M = BSZ*LSEQ, N = K = DM
__global__ __launch_bounds__(TPB) void bx_gemm_kernel(
    const float* __restrict__ X, const float* __restrict__ Bw,
    float* __restrict__ out)
{
    __shared__ float xs[16][68];
    __shared__ float bs[16][68];
    const int bm = blockIdx.x, bn = blockIdx.y;
    const int t  = threadIdx.x;
    const int tx = t & 15, ty = t >> 4;
    const int ml = t >> 2;          // 0..63 row within tile
    const int kq = (t & 3) * 4;     // 0,4,8,12
    const float* xg = X  + (size_t)(bm * 64 + ml) * DM + kq;
    const float* bg = Bw + (size_t)(bn * 64 + ml) * DM + kq;
    float acc[4][4] = {};
    for (int k0 = 0; k0 < DM; k0 += 16) {
        float4 xv = *(const float4*)(xg + k0);
        float4 bv = *(const float4*)(bg + k0);
        __syncthreads();
        xs[kq+0][ml] = xv.x; xs[kq+1][ml] = xv.y; xs[kq+2][ml] = xv.z; xs[kq+3][ml] = xv.w;
        bs[kq+0][ml] = bv.x; bs[kq+1][ml] = bv.y; bs[kq+2][ml] = bv.z; bs[kq+3][ml] = bv.w;
        __syncthreads();
        #pragma unroll
        for (int kk = 0; kk < 16; ++kk) {
            float a[4], c[4];
            #pragma unroll
            for (int i = 0; i < 4; ++i) a[i] = xs[kk][ty*4+i];
            #pragma unroll
            for (int j = 0; j < 4; ++j) c[j] = bs[kk][tx*4+j];
            #pragma unroll
            for (int i = 0; i < 4; ++i)
                #pragma unroll
                for (int j = 0; j < 4; ++j)
                    acc[i][j] += a[i] * c[j];
        }
    }
    #pragma unroll
    for (int i = 0; i < 4; ++i) {
        float4 v = make_float4(acc[i][0], acc[i][1], acc[i][2], acc[i][3]);
        *(float4*)(out + (size_t)(bm*64 + ty*4 + i)*DM + bn*64 + tx*4) = v;
    }
}

// ---------------- Phase 2: fused scan + output projection ----------------
// 64 persistent WGs, flag-synced per step. WG w owns rows [w*16, w*16+16) of
// A and C_w, held in VGPRs. d_out holds bx on entry; y on exit.
// ws: hbuf[2][BSZ][DM] ping-pong (zeroed => s_0 = 0), then int counter.
__global__ __launch_bounds__(TPB) void scan_kernel(
    const float* __restrict__ A, const float* __restrict__ Cw,
    const float* __restrict__ Dv, const float* __restrict__ X,
    float* Y, float* hbuf, int* counter)
{
    __shared__ float hs[BSZ * HROW];   // staged state, seg-padded
    __shared__ float pr[16][PRW];      // A-matvec partials [seg][out]
    __shared__ float pc[16][PRW];      // C-matvec partials
    const int wg  = blockIdx.x;
    const int t   = threadIdx.x;
    const int r   = t & 15;            // row within slice
    const int seg = t >> 4;            // k-segment (64 floats each)
    const int r0  = wg * RPW;

    // A,C slices -> registers (one-time, uncoalesced is fine)
    float ra[64], rc[64];
    {
        const float* Ap = A  + (size_t)(r0 + r) * DM + seg * 64;
        const float* Cp = Cw + (size_t)(r0 + r) * DM + seg * 64;
        #pragma unroll
        for (int u = 0; u < 16; ++u) {
            float4 v = *(const float4*)(Ap + u*4);
            ra[u*4+0]=v.x; ra[u*4+1]=v.y; ra[u*4+2]=v.z; ra[u*4+3]=v.w;
            float4 w = *(const float4*)(Cp + u*4);
            rc[u*4+0]=w.x; rc[u*4+1]=w.y; rc[u*4+2]=w.z; rc[u*4+3]=w.w;
        }
    }
    const float dv = Dv[r0 + r];   // meaningful for t < 64 (reduce threads)

    for (int k = 0; k <= LSEQ; ++k) {
        if (k > 0) {
            if (t == 0) {
                int spins = 0;
                while (__hip_atomic_load(counter, __ATOMIC_RELAXED,
                                         __HIP_MEMORY_SCOPE_AGENT) < NW * k
                       && ++spins < (1 << 18)) {
                    __builtin_amdgcn_s_sleep(1);
                }
            }
            __syncthreads();
            __threadfence();   // acquire: invalidate stale L1/L2 lines
        }
        // stage s_k [BSZ][DM] -> LDS (seg-padded layout)
        const float4* hsrc = (const float4*)(hbuf + (size_t)(k & 1) * BSZ * DM);
        #pragma unroll
        for (int i = 0; i < 4; ++i) {
            int idx = i * TPB + t;       // 0..1023 float4s
            int b   = idx >> 8;
            int f   = idx & 255;
            int sg  = f >> 4;
            int off = f & 15;
            ((float4*)hs)[b * (HROW/4) + sg * (PRW/4) + off] = hsrc[idx];
        }
        __syncthreads();

        // partial dot products: this thread covers (row r, k in [seg*64,seg*64+64))
        float accA[BSZ] = {0.f,0.f,0.f,0.f};
        float accC[BSZ] = {0.f,0.f,0.f,0.f};
        #pragma unroll
        for (int u = 0; u < 16; ++u) {
            #pragma unroll
            for (int b = 0; b < BSZ; ++b) {
                float4 h4 = *(const float4*)(hs + b*HROW + seg*PRW + u*4);
                accA[b] += ra[u*4+0]*h4.x + ra[u*4+1]*h4.y + ra[u*4+2]*h4.z + ra[u*4+3]*h4.w;
                accC[b] += rc[u*4+0]*h4.x + rc[u*4+1]*h4.y + rc[u*4+2]*h4.z + rc[u*4+3]*h4.w;
            }
        }
        #pragma unroll
        for (int b = 0; b < BSZ; ++b) {
            pr[seg][b * RPW + r] = accA[b];
            pc[seg][b * RPW + r] = accC[b];
        }
        __syncthreads();

        if (t < BSZ * RPW) {   // 64 reduce threads: out o = (b, rr)
            const int b = t >> 4, rr = t & 15;
            float sA = 0.f, sC = 0.f;
            #pragma unroll
            for (int s = 0; s < 16; ++s) { sA += pr[s][t]; sC += pc[s][t]; }
            if (k < LSEQ) {
                // s_{k+1} = tanh(A s_k + bx_k); bx_k still in Y, overwrite later by y_k
                const size_t bxoff = (size_t)b*LSEQ*DM + (size_t)k*DM + r0 + rr;
                float hv = tanhf(sA + Y[bxoff]);
                hbuf[(size_t)((k+1)&1)*BSZ*DM + (size_t)b*DM + r0 + rr] = hv;
            }
            if (k > 0) {
                // y_{k-1} = C_w s_k + D * x_{k-1}
                const size_t yoff = (size_t)b*LSEQ*DM + (size_t)(k-1)*DM + r0 + rr;
                Y[yoff] = sC + dv * X[yoff];
            }
        }
        __threadfence();       // release: make h/y writes device-visible
        __syncthreads();
        if (t == 0 && k < LSEQ) atomicAdd(counter, 1);
    }
}

extern "C" void kernel_launch(void* const* d_in, const int* in_sizes, int n_in,
                              void* d_out, int out_size, void* d_ws, size_t ws_size,
                              hipStream_t stream)
{
    const float* X  = (const float*)d_in[0];
    const float* A  = (const float*)d_in[1];
    const float* Bw = (const float*)d_in[2];
    const float* Cw = (const float*)d_in[3];
    const float* Dv = (const float*)d_in[4];
    float* Y    = (float*)d_out;
    float* hbuf = (float*)d_ws;
    int* counter = (int*)((char*)d_ws + (size_t)2 * BSZ * DM * sizeof(float));

    // zero ping-pong state (s_0 = 0) and the step counter every launch
    hipMemsetAsync(d_ws, 0, (size_t)2 * BSZ * DM * sizeof(float) + 256, stream);

    dim3 g1((BSZ * LSEQ) / 64, DM / 64);
    bx_gemm_kernel<<<g1, TPB, 0, stream>>>(X, Bw, Y);
    scan_kernel<<<NW, TPB, 0, stream>>>(A, Cw, Dv, X, Y, hbuf, counter);
}

// Round 2
// 12961.313 us; speedup vs baseline: 4.4811x; 4.4811x over previous
//
#include <hip/hip_runtime.h>
#include <math.h>

#define DM   1024
#define BSZ  4
#define LSEQ 4096
#define GPB  32            // WGs per batch group
#define RPW  32            // rows per WG (DM / GPB)
#define NSEG 8             // column segments (TPB / RPW)
#define CPS  128           // columns per segment (DM / NSEG)
#define TPB  256

typedef unsigned long long u64;

// ---------------- Phase 1: bx = x @ B_w^T (fp32 NT GEMM) ----------------
__global__ __launch_bounds__(TPB) void bx_gemm_kernel(
    const float* __restrict__ X, const float* __restrict__ Bw,
    float* __restrict__ out)
{
    __shared__ float xs[16][68];
    __shared__ float bs[16][68];
    const int bm = blockIdx.x, bn = blockIdx.y;
    const int t  = threadIdx.x;
    const int tx = t & 15, ty = t >> 4;
    const int ml = t >> 2;
    const int kq = (t & 3) * 4;
    const float* xg = X  + (size_t)(bm * 64 + ml) * DM + kq;
    const float* bg = Bw + (size_t)(bn * 64 + ml) * DM + kq;
    float acc[4][4] = {};
    for (int k0 = 0; k0 < DM; k0 += 16) {
        float4 xv = *(const float4*)(xg + k0);
        float4 bv = *(const float4*)(bg + k0);
        __syncthreads();
        xs[kq+0][ml] = xv.x; xs[kq+1][ml] = xv.y; xs[kq+2][ml] = xv.z; xs[kq+3][ml] = xv.w;
        bs[kq+0][ml] = bv.x; bs[kq+1][ml] = bv.y; bs[kq+2][ml] = bv.z; bs[kq+3][ml] = bv.w;
        __syncthreads();
        #pragma unroll
        for (int kk = 0; kk < 16; ++kk) {
            float a[4], c[4];
            #pragma unroll
            for (int i = 0; i < 4; ++i) a[i] = xs[kk][ty*4+i];
            #pragma unroll
            for (int j = 0; j < 4; ++j) c[j] = bs[kk][tx*4+j];
            #pragma unroll
            for (int i = 0; i < 4; ++i)
                #pragma unroll
                for (int j = 0; j < 4; ++j)
                    acc[i][j] += a[i] * c[j];
        }
    }
    #pragma unroll
    for (int i = 0; i < 4; ++i) {
        float4 v = make_float4(acc[i][0], acc[i][1], acc[i][2], acc[i][3]);
        *(float4*)(out + (size_t)(bm*64 + ty*4 + i)*DM + bn*64 + tx*4) = v;
    }
}

// ---------------- Phase 2: fused scan, batch-split, tagged-atomic sync ----
// 128 WGs = 4 batch groups x 32. WG owns 32 rows of A and C_w in VGPRs.
// State exchanged as (tag<<32 | float) u64 agent-scope relaxed atomics in
// hbuf[2][BSZ][DM]; slot parity = tag & 1. Zero-init => s_0 = 0 with tag 0.
__global__ __launch_bounds__(TPB, 1) void scan_kernel(
    const float* __restrict__ A, const float* __restrict__ Cw,
    const float* __restrict__ Dv, const float* __restrict__ X,
    float* __restrict__ Y, u64* hbuf)
{
    __shared__ float hs[DM];             // staged s_k for this batch
    __shared__ float pA[NSEG][RPW + 1];  // partials [seg][row]
    __shared__ float pC[NSEG][RPW + 1];
    const int b   = blockIdx.x >> 5;     // batch
    const int gw  = blockIdx.x & 31;     // group-local WG
    const int r0  = gw * RPW;
    const int t   = threadIdx.x;
    const int r   = t & 31;              // row within slice
    const int seg = t >> 5;              // column segment

    // A, C row-slices -> registers (one time)
    float ra[CPS], rc[CPS];
    {
        const float* Ap = A  + (size_t)(r0 + r) * DM + seg * CPS;
        const float* Cp = Cw + (size_t)(r0 + r) * DM + seg * CPS;
        #pragma unroll
        for (int u = 0; u < CPS / 4; ++u) {
            float4 v = *(const float4*)(Ap + u*4);
            ra[u*4+0]=v.x; ra[u*4+1]=v.y; ra[u*4+2]=v.z; ra[u*4+3]=v.w;
            float4 w = *(const float4*)(Cp + u*4);
            rc[u*4+0]=w.x; rc[u*4+1]=w.y; rc[u*4+2]=w.z; rc[u*4+3]=w.w;
        }
    }
    const float dv = Dv[r0 + (t & 31)];  // valid for reduce threads (t < 32)

    for (int k = 0; k <= LSEQ; ++k) {
        // ---- acquire s_k: poll tagged u64s, stage float part to LDS ----
        u64* src = hbuf + (size_t)(k & 1) * BSZ * DM + (size_t)b * DM;
        u64 v0 = __hip_atomic_load(src + t,       __ATOMIC_RELAXED, __HIP_MEMORY_SCOPE_AGENT);
        u64 v1 = __hip_atomic_load(src + t + 256, __ATOMIC_RELAXED, __HIP_MEMORY_SCOPE_AGENT);
        u64 v2 = __hip_atomic_load(src + t + 512, __ATOMIC_RELAXED, __HIP_MEMORY_SCOPE_AGENT);
        u64 v3 = __hip_atomic_load(src + t + 768, __ATOMIC_RELAXED, __HIP_MEMORY_SCOPE_AGENT);
        const unsigned tag = (unsigned)k;
        int spins = 0;
        while ((((unsigned)(v0 >> 32)) != tag || ((unsigned)(v1 >> 32)) != tag ||
                ((unsigned)(v2 >> 32)) != tag || ((unsigned)(v3 >> 32)) != tag)
               && ++spins < (1 << 20)) {
            if ((unsigned)(v0 >> 32) != tag)
                v0 = __hip_atomic_load(src + t,       __ATOMIC_RELAXED, __HIP_MEMORY_SCOPE_AGENT);
            if ((unsigned)(v1 >> 32) != tag)
                v1 = __hip_atomic_load(src + t + 256, __ATOMIC_RELAXED, __HIP_MEMORY_SCOPE_AGENT);
            if ((unsigned)(v2 >> 32) != tag)
                v2 = __hip_atomic_load(src + t + 512, __ATOMIC_RELAXED, __HIP_MEMORY_SCOPE_AGENT);
            if ((unsigned)(v3 >> 32) != tag)
                v3 = __hip_atomic_load(src + t + 768, __ATOMIC_RELAXED, __HIP_MEMORY_SCOPE_AGENT);
        }
        hs[t]       = __uint_as_float((unsigned)v0);
        hs[t + 256] = __uint_as_float((unsigned)v1);
        hs[t + 512] = __uint_as_float((unsigned)v2);
        hs[t + 768] = __uint_as_float((unsigned)v3);
        __syncthreads();

        // ---- partial dots over this thread's 128-column segment ----
        float accA = 0.f, accC = 0.f;
        const float4* h4p = (const float4*)(hs + seg * CPS);
        #pragma unroll
        for (int u = 0; u < CPS / 4; ++u) {
            float4 h4 = h4p[u];
            accA += ra[u*4+0]*h4.x + ra[u*4+1]*h4.y + ra[u*4+2]*h4.z + ra[u*4+3]*h4.w;
            accC += rc[u*4+0]*h4.x + rc[u*4+1]*h4.y + rc[u*4+2]*h4.z + rc[u*4+3]*h4.w;
        }
        pA[seg][r] = accA;
        pC[seg][r] = accC;
        __syncthreads();

        // ---- reduce + state write + y write (32 threads) ----
        if (t < RPW) {
            float sA = 0.f, sC = 0.f;
            #pragma unroll
            for (int s = 0; s < NSEG; ++s) { sA += pA[s][t]; sC += pC[s][t]; }
            if (k < LSEQ) {
                const size_t bxoff = (size_t)b*LSEQ*DM + (size_t)k*DM + r0 + t;
                float hv = tanhf(sA + Y[bxoff]);       // bx_k still in Y here
                u64 pk = ((u64)(unsigned)(k + 1) << 32) | (u64)__float_as_uint(hv);
                __hip_atomic_store(hbuf + (size_t)((k+1) & 1) * BSZ * DM + (size_t)b * DM + r0 + t,
                                   pk, __ATOMIC_RELAXED, __HIP_MEMORY_SCOPE_AGENT);
            }
            if (k > 0) {
                const size_t yoff = (size_t)b*LSEQ*DM + (size_t)(k-1)*DM + r0 + t;
                Y[yoff] = sC + dv * X[yoff];           // y_{k-1} = C s_k + D x_{k-1}
            }
        }
        // no trailing barrier needed: pA/pC(k+1) writes sit behind the
        // post-stage __syncthreads of iteration k+1, which reducers must reach.
    }
}

extern "C" void kernel_launch(void* const* d_in, const int* in_sizes, int n_in,
                              void* d_out, int out_size, void* d_ws, size_t ws_size,
                              hipStream_t stream)
{
    const float* X  = (const float*)d_in[0];
    const float* A  = (const float*)d_in[1];
    const float* Bw = (const float*)d_in[2];
    const float* Cw = (const float*)d_in[3];
    const float* Dv = (const float*)d_in[4];
    float* Y   = (float*)d_out;
    u64* hbuf  = (u64*)d_ws;

    // zero tagged state every launch: (0.0f, tag 0) == s_0 ready
    hipMemsetAsync(d_ws, 0, (size_t)2 * BSZ * DM * sizeof(u64), stream);

    dim3 g1((BSZ * LSEQ) / 64, DM / 64);
    bx_gemm_kernel<<<g1, TPB, 0, stream>>>(X, Bw, Y);
    scan_kernel<<<BSZ * GPB, TPB, 0, stream>>>(A, Cw, Dv, X, Y, hbuf);
}

// Round 3
// 11513.626 us; speedup vs baseline: 5.0445x; 1.1257x over previous
//
#include <hip/hip_runtime.h>
#include <math.h>

#define DM   1024
#define BSZ  4
#define LSEQ 4096
#define GPB  32            // WGs per batch group
#define RPW  32            // rows per WG (DM / GPB)
#define TPB  256
#define SP   132           // padded words per 128-col segment
#define HSW  1056          // 8 * SP, padded words per 1024-col row
#define RS   1056          // LDS row stride for C slice (33*32 words)

typedef unsigned long long u64;

// ---------------- Phase 1: bx = x @ B_w^T (fp32 NT GEMM) ----------------
__global__ __launch_bounds__(TPB) void bx_gemm_kernel(
    const float* __restrict__ X, const float* __restrict__ Bw,
    float* __restrict__ out)
{
    __shared__ float xs[16][68];
    __shared__ float bs[16][68];
    const int bm = blockIdx.x, bn = blockIdx.y;
    const int t  = threadIdx.x;
    const int tx = t & 15, ty = t >> 4;
    const int ml = t >> 2;
    const int kq = (t & 3) * 4;
    const float* xg = X  + (size_t)(bm * 64 + ml) * DM + kq;
    const float* bg = Bw + (size_t)(bn * 64 + ml) * DM + kq;
    float acc[4][4] = {};
    for (int k0 = 0; k0 < DM; k0 += 16) {
        float4 xv = *(const float4*)(xg + k0);
        float4 bv = *(const float4*)(bg + k0);
        __syncthreads();
        xs[kq+0][ml] = xv.x; xs[kq+1][ml] = xv.y; xs[kq+2][ml] = xv.z; xs[kq+3][ml] = xv.w;
        bs[kq+0][ml] = bv.x; bs[kq+1][ml] = bv.y; bs[kq+2][ml] = bv.z; bs[kq+3][ml] = bv.w;
        __syncthreads();
        #pragma unroll
        for (int kk = 0; kk < 16; ++kk) {
            float a[4], c[4];
            #pragma unroll
            for (int i = 0; i < 4; ++i) a[i] = xs[kk][ty*4+i];
            #pragma unroll
            for (int j = 0; j < 4; ++j) c[j] = bs[kk][tx*4+j];
            #pragma unroll
            for (int i = 0; i < 4; ++i)
                #pragma unroll
                for (int j = 0; j < 4; ++j)
                    acc[i][j] += a[i] * c[j];
        }
    }
    #pragma unroll
    for (int i = 0; i < 4; ++i) {
        float4 v = make_float4(acc[i][0], acc[i][1], acc[i][2], acc[i][3]);
        *(float4*)(out + (size_t)(bm*64 + ty*4 + i)*DM + bn*64 + tx*4) = v;
    }
}

// ---------------- Phase 2: fused scan, batch-split, tagged-atomic sync ----
// 128 WGs = 4 batch groups x 32. WG owns 32 rows: A slice in VGPRs (128/thr),
// C slice in LDS (132KB). Thread t: row = t>>3, col-seg = t&7 (128 cols).
// Row-sum via __shfl_xor over 8 consecutive lanes. State exchanged as
// (tag<<32|float) u64 agent-scope relaxed atomics; slot parity = tag & 1.
// Critical path per step: poll -> stage -> A-matvec -> shfl -> tanh -> store.
// C-matvec + y-store deferred after the h-store (overlaps next poll).
__global__ __launch_bounds__(TPB, 1) void scan_kernel(
    const float* __restrict__ A, const float* __restrict__ Cw,
    const float* __restrict__ Dv, const float* __restrict__ X,
    float* __restrict__ Y, u64* hbuf)
{
    extern __shared__ float lds[];          // [RPW*RS] C slice | [HSW] staged h
    float* cs = lds;
    float* hs = lds + RPW * RS;
    const int b   = blockIdx.x >> 5;        // batch
    const int gw  = blockIdx.x & 31;        // group-local WG
    const int r0  = gw * RPW;
    const int t   = threadIdx.x;
    const int row = t >> 3;                 // 0..31 row within slice
    const int seg = t & 7;                  // 128-col segment
    const bool lead = (seg == 0);

    // A row-slice -> registers (128 floats/thread)
    float ra[128];
    {
        const float* Ap = A + (size_t)(r0 + row) * DM + seg * 128;
        #pragma unroll
        for (int u = 0; u < 32; ++u) {
            float4 v = *(const float4*)(Ap + u*4);
            ra[u*4+0]=v.x; ra[u*4+1]=v.y; ra[u*4+2]=v.z; ra[u*4+3]=v.w;
        }
    }
    // C row-slice -> LDS (coalesced), padded layout
    for (int i = 0; i < 32; ++i) {
        int idx = i * TPB + t;              // float4 index, 8192 total
        int rr  = idx >> 8;
        int c   = (idx & 255) * 4;
        float4 v = *(const float4*)(Cw + (size_t)(r0 + rr) * DM + c);
        *(float4*)(cs + rr * RS + (c >> 7) * SP + (c & 127)) = v;
    }
    const float dv = Dv[r0 + row];
    __syncthreads();

    for (int k = 0; k <= LSEQ; ++k) {
        // bx prefetch (independent load, completes during poll)
        float bxv = 0.f;
        if (lead && k < LSEQ)
            bxv = Y[(size_t)b*LSEQ*DM + (size_t)k*DM + r0 + row];

        // ---- acquire s_k: poll tagged u64s, stage to padded LDS ----
        u64* src = hbuf + (size_t)(k & 1) * BSZ * DM + (size_t)b * DM;
        u64 v0 = __hip_atomic_load(src + t,       __ATOMIC_RELAXED, __HIP_MEMORY_SCOPE_AGENT);
        u64 v1 = __hip_atomic_load(src + t + 256, __ATOMIC_RELAXED, __HIP_MEMORY_SCOPE_AGENT);
        u64 v2 = __hip_atomic_load(src + t + 512, __ATOMIC_RELAXED, __HIP_MEMORY_SCOPE_AGENT);
        u64 v3 = __hip_atomic_load(src + t + 768, __ATOMIC_RELAXED, __HIP_MEMORY_SCOPE_AGENT);
        const unsigned tag = (unsigned)k;
        int spins = 0;
        while ((((unsigned)(v0 >> 32)) != tag || ((unsigned)(v1 >> 32)) != tag ||
                ((unsigned)(v2 >> 32)) != tag || ((unsigned)(v3 >> 32)) != tag)
               && ++spins < (1 << 20)) {
            if ((unsigned)(v0 >> 32) != tag)
                v0 = __hip_atomic_load(src + t,       __ATOMIC_RELAXED, __HIP_MEMORY_SCOPE_AGENT);
            if ((unsigned)(v1 >> 32) != tag)
                v1 = __hip_atomic_load(src + t + 256, __ATOMIC_RELAXED, __HIP_MEMORY_SCOPE_AGENT);
            if ((unsigned)(v2 >> 32) != tag)
                v2 = __hip_atomic_load(src + t + 512, __ATOMIC_RELAXED, __HIP_MEMORY_SCOPE_AGENT);
            if ((unsigned)(v3 >> 32) != tag)
                v3 = __hip_atomic_load(src + t + 768, __ATOMIC_RELAXED, __HIP_MEMORY_SCOPE_AGENT);
        }
        {
            int c0 = t, c1 = t + 256, c2 = t + 512, c3 = t + 768;
            hs[(c0 >> 7) * SP + (c0 & 127)] = __uint_as_float((unsigned)v0);
            hs[(c1 >> 7) * SP + (c1 & 127)] = __uint_as_float((unsigned)v1);
            hs[(c2 >> 7) * SP + (c2 & 127)] = __uint_as_float((unsigned)v2);
            hs[(c3 >> 7) * SP + (c3 & 127)] = __uint_as_float((unsigned)v3);
        }
        __syncthreads();

        // ---- critical path: A-matvec over this thread's 128-col segment ----
        float accA = 0.f;
        {
            const float4* h4p = (const float4*)(hs + seg * SP);
            #pragma unroll
            for (int u = 0; u < 32; ++u) {
                float4 h4 = h4p[u];
                accA += ra[u*4+0]*h4.x + ra[u*4+1]*h4.y + ra[u*4+2]*h4.z + ra[u*4+3]*h4.w;
            }
        }
        accA += __shfl_xor(accA, 1);
        accA += __shfl_xor(accA, 2);
        accA += __shfl_xor(accA, 4);
        if (lead && k < LSEQ) {
            float hv = tanhf(accA + bxv);
            u64 pk = ((u64)(unsigned)(k + 1) << 32) | (u64)__float_as_uint(hv);
            __hip_atomic_store(hbuf + (size_t)((k+1) & 1) * BSZ * DM + (size_t)b * DM + r0 + row,
                               pk, __ATOMIC_RELAXED, __HIP_MEMORY_SCOPE_AGENT);
        }

        // ---- deferred: C-matvec + y-store (overlaps next step's wait) ----
        if (k > 0) {
            float accC = 0.f;
            const float4* c4p = (const float4*)(cs + row * RS + seg * SP);
            const float4* h4p = (const float4*)(hs + seg * SP);
            #pragma unroll
            for (int u = 0; u < 32; ++u) {
                float4 c4 = c4p[u];
                float4 h4 = h4p[u];
                accC += c4.x*h4.x + c4.y*h4.y + c4.z*h4.z + c4.w*h4.w;
            }
            accC += __shfl_xor(accC, 1);
            accC += __shfl_xor(accC, 2);
            accC += __shfl_xor(accC, 4);
            if (lead) {
                const size_t yoff = (size_t)b*LSEQ*DM + (size_t)(k-1)*DM + r0 + row;
                Y[yoff] = accC + dv * X[yoff];   // y_{k-1} = C s_k + D x_{k-1}
            }
        }
        __syncthreads();   // hs stable until all threads done reading it
    }
}

extern "C" void kernel_launch(void* const* d_in, const int* in_sizes, int n_in,
                              void* d_out, int out_size, void* d_ws, size_t ws_size,
                              hipStream_t stream)
{
    const float* X  = (const float*)d_in[0];
    const float* A  = (const float*)d_in[1];
    const float* Bw = (const float*)d_in[2];
    const float* Cw = (const float*)d_in[3];
    const float* Dv = (const float*)d_in[4];
    float* Y   = (float*)d_out;
    u64* hbuf  = (u64*)d_ws;

    // zero tagged state every launch: (0.0f, tag 0) == s_0 ready
    hipMemsetAsync(d_ws, 0, (size_t)2 * BSZ * DM * sizeof(u64), stream);

    dim3 g1((BSZ * LSEQ) / 64, DM / 64);
    bx_gemm_kernel<<<g1, TPB, 0, stream>>>(X, Bw, Y);
    const size_t lds_bytes = (size_t)(RPW * RS + HSW) * sizeof(float);
    scan_kernel<<<BSZ * GPB, TPB, lds_bytes, stream>>>(A, Cw, Dv, X, Y, hbuf);
}